// Round 5
// baseline (684.914 us; speedup 1.0000x reference)
//
#include <hip/hip_runtime.h>
#include <hip/hip_fp16.h>

// ---------------------------------------------------------------------------
// LinkPredictionGNN: 2x GCNConv (self-loops, sym-norm) + pair MLP head.
//   deg/dinv + CSR build (count, scan, scatter)         [int kernels]
//   prep: W1/W2/Wh1_top/Wh1_bot -> bf16 hi/lo B-frags   [k_prep_w, 256KB]
//   g1 = fp16( dinv * (x @ W1) )                        [k_gemm_mfma]
//   h1 = relu(dinv * (gather-sum g1 + g1) + b1)         [agg_h, fp16 gather]
//   g2 = fp16( dinv * (h1 @ W2) )                       [k_gemm_mfma]
//   h2 = relu(dinv * (gather-sum g2 + g2) + b2)         [agg_h]
//   A = fp16(h2 @ Wh1_top), B = fp16(h2 @ Wh1_bot)      [k_gemm_mfma x2]
//   out[p] = relu(A[p0]+B[p1]+bh1) . Wh2 + bh2          [pairs_h]
//
// R1: scatter write-amplification fixed (partially) via dst-range partition.
// R2: fp16 message/A/B tables halve gather bytes (absmax 4.9e-4 < 1.5e-3).
// R3: double-bf16-split MFMA GEMM (Ah.Bh+Al.Bh+Ah.Bl), no LDS/barriers.
// R4: scatter WRITE still 67MB for 6.4MB payload -> blockIdx%8 XCD-affinity
// assumption fails + stream eviction. Now range = physical XCC_ID (hwreg),
// ticket-based chunk distribution per range (+ fall-through over all ranges
// for correctness under any block->XCD mapping), and NON-TEMPORAL loads for
// the edge streams so dirty scatter lines stay L2-resident until full.
// ---------------------------------------------------------------------------

#define NRANGE 8
#define CHUNKS 256   // work chunks per range (ticket-distributed)

typedef __attribute__((ext_vector_type(8))) short bf16x8;
typedef __attribute__((ext_vector_type(4))) float f32x4;

__device__ __forceinline__ int get_xcc_id() {
  unsigned x;
  asm volatile("s_getreg_b32 %0, hwreg(HW_REG_XCC_ID, 0, 4)" : "=s"(x));
  return (int)(x & 7u);
}

__global__ __launch_bounds__(256) void k_zero_i32(int* __restrict__ p, int n) {
  int i = blockIdx.x * 256 + threadIdx.x;
  if (i < n) p[i] = 0;
}

// XCD-affine degree count: block serves the node range owned by its physical
// XCD (deg window ~25KB stays in this XCD's L2); nt loads keep the dst
// stream from evicting it. Falls through to other ranges for correctness.
__global__ __launch_bounds__(256) void k_count_x(const int* __restrict__ dst,
                                                 int* __restrict__ deg,
                                                 int* __restrict__ ticket,
                                                 int e, int rsz) {
  int xcc = get_xcc_id();
  int ch = (e + CHUNKS - 1) / CHUNKS;
  __shared__ int s_chunk;
  for (int rr = 0; rr < NRANGE; ++rr) {
    int range = (xcc + rr) & (NRANGE - 1);
    int lo = range * rsz, hi = lo + rsz;
    for (;;) {
      if (threadIdx.x == 0) s_chunk = atomicAdd(&ticket[range], 1);
      __syncthreads();
      int chunk = s_chunk;
      __syncthreads();
      if (chunk >= CHUNKS) break;
      int beg = chunk * ch + threadIdx.x;
      int end = min(e, (chunk + 1) * ch);
      for (int i = beg; i < end; i += 256) {
        int d = __builtin_nontemporal_load(&dst[i]);
        if (d >= lo && d < hi) atomicAdd(&deg[d], 1);
      }
    }
  }
}

__device__ __forceinline__ int block_excl_scan_256(int v, int* lds) {
  int lane = threadIdx.x & 63;
  int wid = threadIdx.x >> 6;
  int orig = v;
#pragma unroll
  for (int o = 1; o < 64; o <<= 1) {
    int u = __shfl_up(v, o, 64);
    if (lane >= o) v += u;
  }
  if (lane == 63) lds[wid] = v;
  __syncthreads();
  int woff = 0;
#pragma unroll
  for (int w = 0; w < 4; ++w)
    if (w < wid) woff += lds[w];
  return woff + v - orig;
}

__global__ __launch_bounds__(256) void k_block_sum(const int* __restrict__ deg,
                                                   int* __restrict__ bsum, int n) {
  __shared__ int lds[4];
  int i = blockIdx.x * 256 + threadIdx.x;
  int v = (i < n) ? deg[i] : 0;
#pragma unroll
  for (int o = 32; o > 0; o >>= 1) v += __shfl_down(v, o, 64);
  if ((threadIdx.x & 63) == 0) lds[threadIdx.x >> 6] = v;
  __syncthreads();
  if (threadIdx.x == 0) bsum[blockIdx.x] = lds[0] + lds[1] + lds[2] + lds[3];
}

__global__ __launch_bounds__(256) void k_scan_bsums(const int* __restrict__ bsum,
                                                    int* __restrict__ boff, int nb) {
  __shared__ int lds[4];
  int t = threadIdx.x;
  int v = (t < nb) ? bsum[t] : 0;
  int e = block_excl_scan_256(v, lds);
  if (t < nb) boff[t] = e;
}

__global__ __launch_bounds__(256) void k_scan_final(
    const int* __restrict__ deg, const int* __restrict__ boff,
    int* __restrict__ rowptr, int* __restrict__ cursor,
    float* __restrict__ dinv, int n, int e_total) {
  __shared__ int lds[4];
  int i = blockIdx.x * 256 + threadIdx.x;
  int v = (i < n) ? deg[i] : 0;
  int ex = block_excl_scan_256(v, lds);
  if (i < n) {
    int rp = boff[blockIdx.x] + ex;
    rowptr[i] = rp;
    cursor[i] = rp;
    dinv[i] = rsqrtf((float)(v + 1));  // +1 self loop; always > 0
  }
  if (i == 0) rowptr[n] = e_total;
}

// XCD-affine scatter: colarr window (~800KB) + cursor window (~25KB) for a
// range are written only from the owning XCD; nt edge-stream loads.
__global__ __launch_bounds__(256) void k_scatter_x(const int* __restrict__ src,
                                                   const int* __restrict__ dst,
                                                   int* __restrict__ cursor,
                                                   int* __restrict__ colarr,
                                                   int* __restrict__ ticket,
                                                   int e, int rsz) {
  int xcc = get_xcc_id();
  int ch = (e + CHUNKS - 1) / CHUNKS;
  __shared__ int s_chunk;
  for (int rr = 0; rr < NRANGE; ++rr) {
    int range = (xcc + rr) & (NRANGE - 1);
    int lo = range * rsz, hi = lo + rsz;
    for (;;) {
      if (threadIdx.x == 0) s_chunk = atomicAdd(&ticket[range], 1);
      __syncthreads();
      int chunk = s_chunk;
      __syncthreads();
      if (chunk >= CHUNKS) break;
      int beg = chunk * ch + threadIdx.x;
      int end = min(e, (chunk + 1) * ch);
      for (int i = beg; i < end; i += 256) {
        int d = __builtin_nontemporal_load(&dst[i]);
        if (d >= lo && d < hi) {
          int s = __builtin_nontemporal_load(&src[i]);
          int pos = atomicAdd(&cursor[d], 1);
          colarr[pos] = s;
        }
      }
    }
  }
}

// --- MFMA GEMM machinery ----------------------------------------------------
// Exact split: x = hi(bf16, trunc) + lo(bf16, trunc) + O(2^-17 |x|).
__device__ __forceinline__ void split8(const float* v, bf16x8& hi, bf16x8& lo) {
#pragma unroll
  for (int j = 0; j < 8; ++j) {
    unsigned u = __float_as_uint(v[j]);
    hi[j] = (short)(u >> 16);
    float lf = v[j] - __uint_as_float(u & 0xffff0000u);
    lo[j] = (short)(__float_as_uint(lf) >> 16);
  }
}

// Precompute B-operand bf16 hi/lo fragments for the 4 weight matrices.
// Slot g = ((w*8 + t)*4 + s)*64 + lane ; lane holds B[k=s*32+quad*8+j][n=16t+(lane&15)]
__global__ __launch_bounds__(256) void k_prep_w(
    const float* __restrict__ W1, const float* __restrict__ W2,
    const float* __restrict__ Wh1, short* __restrict__ fragH,
    short* __restrict__ fragL) {
  int g = blockIdx.x * 256 + threadIdx.x;
  if (g >= 4 * 2048) return;
  int w = g >> 11;
  int rem = g & 2047;
  int lane = rem & 63;
  int ts = rem >> 6;          // t*4 + s
  int t = ts >> 2, s = ts & 3;
  int n = (t << 4) + (lane & 15);
  int k0 = s * 32 + (lane >> 4) * 8;
  const float* W = (w == 0) ? W1 : (w == 1) ? W2 : (w == 2) ? Wh1 : (Wh1 + 128 * 128);
  short h[8], l[8];
#pragma unroll
  for (int j = 0; j < 8; ++j) {
    float x = W[(k0 + j) * 128 + n];
    unsigned u = __float_as_uint(x);
    h[j] = (short)(u >> 16);
    float lf = x - __uint_as_float(u & 0xffff0000u);
    l[j] = (short)(__float_as_uint(lf) >> 16);
  }
  ((int4*)fragH)[g] = *(int4*)h;
  ((int4*)fragL)[g] = *(int4*)l;
}

// C16[n,128] = fp16( rowscale * (X[n,128] @ W) ) via 16x16x32 bf16 MFMA.
// One wave = 16 rows x 128 cols. No LDS, no barriers.
__global__ __launch_bounds__(256) void k_gemm_mfma(
    const float* __restrict__ X, const short* __restrict__ fragH,
    const short* __restrict__ fragL, const float* __restrict__ rowscale,
    __half* __restrict__ C16, int n) {
  int wid = threadIdx.x >> 6, lane = threadIdx.x & 63;
  int r0 = (blockIdx.x * 4 + wid) * 16;
  if (r0 >= n) return;
  int m = lane & 15, quad = lane >> 4;
  const float* xrow = X + (size_t)(r0 + m) * 128;
  f32x4 acc[8];
#pragma unroll
  for (int t = 0; t < 8; ++t) acc[t] = (f32x4)(0.f);
  const int4* FH = (const int4*)fragH;
  const int4* FL = (const int4*)fragL;
#pragma unroll
  for (int s = 0; s < 4; ++s) {
    int k0 = s * 32 + quad * 8;
    float xv[8];
    *(float4*)&xv[0] = *(const float4*)(xrow + k0);
    *(float4*)&xv[4] = *(const float4*)(xrow + k0 + 4);
    bf16x8 ah, al;
    split8(xv, ah, al);
#pragma unroll
    for (int t = 0; t < 8; ++t) {
      int idx = (t * 4 + s) * 64 + lane;
      bf16x8 bh = *(const bf16x8*)&FH[idx];
      bf16x8 bl = *(const bf16x8*)&FL[idx];
      acc[t] = __builtin_amdgcn_mfma_f32_16x16x32_bf16(ah, bh, acc[t], 0, 0, 0);
      acc[t] = __builtin_amdgcn_mfma_f32_16x16x32_bf16(al, bh, acc[t], 0, 0, 0);
      acc[t] = __builtin_amdgcn_mfma_f32_16x16x32_bf16(ah, bl, acc[t], 0, 0, 0);
    }
  }
  // C/D layout: col = lane&15, row = quad*4 + reg   [m89-verified mapping]
  float sc[4];
#pragma unroll
  for (int r = 0; r < 4; ++r)
    sc[r] = rowscale ? rowscale[r0 + quad * 4 + r] : 1.f;
#pragma unroll
  for (int t = 0; t < 8; ++t) {
#pragma unroll
    for (int r = 0; r < 4; ++r) {
      int row = r0 + quad * 4 + r;
      C16[(size_t)row * 128 + t * 16 + m] = __float2half(acc[t][r] * sc[r]);
    }
  }
}

// out[i,:] = relu(dinv[i] * (g[i,:] + sum_{e in row i} g[col[e],:]) + bias)
// fp16 message table; 64 lanes per row, one half2 (2 cols) per lane.
__global__ __launch_bounds__(256) void k_agg_h(
    const __half2* __restrict__ g2, const float* __restrict__ dinv,
    const int* __restrict__ rowptr, const int* __restrict__ col,
    const float* __restrict__ bias, float* __restrict__ out, int n) {
  int i = blockIdx.x * 4 + (threadIdx.x >> 6);
  int c = threadIdx.x & 63;  // half2 column index
  if (i >= n) return;
  float2 a0 = __half22float2(g2[(size_t)i * 64 + c]);  // self loop
  float2 a1 = make_float2(0.f, 0.f);
  float2 a2 = make_float2(0.f, 0.f);
  float2 a3 = make_float2(0.f, 0.f);
  int beg = rowptr[i], end = rowptr[i + 1];
  int j = beg;
  for (; j + 4 <= end; j += 4) {
    int s0 = __builtin_nontemporal_load(&col[j]);
    int s1 = __builtin_nontemporal_load(&col[j + 1]);
    int s2 = __builtin_nontemporal_load(&col[j + 2]);
    int s3 = __builtin_nontemporal_load(&col[j + 3]);
    float2 v0 = __half22float2(g2[(size_t)s0 * 64 + c]);
    float2 v1 = __half22float2(g2[(size_t)s1 * 64 + c]);
    float2 v2 = __half22float2(g2[(size_t)s2 * 64 + c]);
    float2 v3 = __half22float2(g2[(size_t)s3 * 64 + c]);
    a0.x += v0.x; a0.y += v0.y;
    a1.x += v1.x; a1.y += v1.y;
    a2.x += v2.x; a2.y += v2.y;
    a3.x += v3.x; a3.y += v3.y;
  }
  for (; j < end; ++j) {
    float2 v = __half22float2(g2[(size_t)__builtin_nontemporal_load(&col[j]) * 64 + c]);
    a0.x += v.x; a0.y += v.y;
  }
  float di = dinv[i];
  float2 bi = ((const float2*)bias)[c];
  float2 o;
  o.x = fmaxf(fmaf(di, (a0.x + a1.x) + (a2.x + a3.x), bi.x), 0.f);
  o.y = fmaxf(fmaf(di, (a0.y + a1.y) + (a2.y + a3.y), bi.y), 0.f);
  ((float2*)out)[(size_t)i * 64 + c] = o;
}

// one wave per pair, fp16 A/B tables, half2 per lane
__global__ __launch_bounds__(256) void k_pairs_h(
    const __half2* __restrict__ A, const __half2* __restrict__ B,
    const int* __restrict__ pairs, const float* __restrict__ bh1,
    const float* __restrict__ wh2, const float* __restrict__ bh2,
    float* __restrict__ out, int P) {
  int p = blockIdx.x * 4 + (threadIdx.x >> 6);
  int c = threadIdx.x & 63;
  if (p >= P) return;
  int p0 = pairs[2 * p], p1 = pairs[2 * p + 1];
  float2 av = __half22float2(A[(size_t)p0 * 64 + c]);
  float2 bv = __half22float2(B[(size_t)p1 * 64 + c]);
  float2 bi = ((const float2*)bh1)[c];
  float2 wv = ((const float2*)wh2)[c];
  float v0 = fmaxf(av.x + bv.x + bi.x, 0.f) * wv.x;
  float v1 = fmaxf(av.y + bv.y + bi.y, 0.f) * wv.y;
  float s = v0 + v1;
#pragma unroll
  for (int o = 32; o > 0; o >>= 1) s += __shfl_down(s, o, 64);
  if (c == 0) out[p] = s + bh2[0];
}

extern "C" void kernel_launch(void* const* d_in, const int* in_sizes, int n_in,
                              void* d_out, int out_size, void* d_ws, size_t ws_size,
                              hipStream_t stream) {
  const float* x   = (const float*)d_in[0];
  const int* ei    = (const int*)d_in[1];
  const int* pairs = (const int*)d_in[2];
  const float* W1  = (const float*)d_in[3];
  const float* b1  = (const float*)d_in[4];
  const float* W2  = (const float*)d_in[5];
  const float* b2  = (const float*)d_in[6];
  const float* Wh1 = (const float*)d_in[7];
  const float* bh1 = (const float*)d_in[8];
  const float* Wh2 = (const float*)d_in[9];
  const float* bh2 = (const float*)d_in[10];
  (void)n_in; (void)out_size; (void)ws_size;

  int N = in_sizes[0] / 128;
  int E = in_sizes[1] / 2;
  int P = in_sizes[2] / 2;
  const int* src = ei;
  const int* dst = ei + E;

  char* wsp = (char*)d_ws;
  size_t off = 0;
  auto alloc = [&](size_t bytes) -> void* {
    void* p = wsp + off;
    off += (bytes + 255) & ~(size_t)255;
    return p;
  };
  __half* g16 = (__half*)alloc((size_t)N * 128 * 2);  // messages; reused as A16
  float* h1   = (float*)alloc((size_t)N * 128 * 4);   // reused as B16 (fp16)
  float* h2   = (float*)alloc((size_t)N * 128 * 4);
  float* dinv = (float*)alloc((size_t)N * 4);
  int* deg    = (int*)alloc((size_t)N * 4);
  int* rowptr = (int*)alloc((size_t)(N + 1) * 4);
  int* cursor = (int*)alloc((size_t)N * 4);
  int* colarr = (int*)alloc((size_t)E * 4);
  short* fragH = (short*)alloc(4 * 2048 * 8 * 2);  // 128KB
  short* fragL = (short*)alloc(4 * 2048 * 8 * 2);  // 128KB
  int* ticket  = (int*)alloc(2 * NRANGE * 4);      // [0:8) count, [8:16) scatter
  int NB = (N + 255) / 256;
  int* bsum = (int*)alloc((size_t)NB * 4);
  int* boff = (int*)alloc((size_t)NB * 4);
  __half* A16 = g16;            // g16 dead by the time head runs
  __half* B16 = (__half*)h1;    // h1 dead after conv2 gemm
  // per-W frag bases (2048 slots * 8 shorts each)
  short* fH_W1 = fragH + 0 * 16384;  short* fL_W1 = fragL + 0 * 16384;
  short* fH_W2 = fragH + 1 * 16384;  short* fL_W2 = fragL + 1 * 16384;
  short* fH_Wa = fragH + 2 * 16384;  short* fL_Wa = fragL + 2 * 16384;
  short* fH_Wb = fragH + 3 * 16384;  short* fL_Wb = fragL + 3 * 16384;

  int rsz = (N + NRANGE - 1) / NRANGE;  // nodes per range

  // weight fragment prep (independent of CSR)
  k_prep_w<<<32, 256, 0, stream>>>(W1, W2, Wh1, fragH, fragL);

  // CSR + degree
  k_zero_i32<<<(N + 255) / 256, 256, 0, stream>>>(deg, N);
  k_zero_i32<<<1, 64, 0, stream>>>(ticket, 2 * NRANGE);
  k_count_x<<<1024, 256, 0, stream>>>(dst, deg, ticket, E, rsz);
  k_block_sum<<<NB, 256, 0, stream>>>(deg, bsum, N);
  k_scan_bsums<<<1, 256, 0, stream>>>(bsum, boff, NB);
  k_scan_final<<<NB, 256, 0, stream>>>(deg, boff, rowptr, cursor, dinv, N, E);
  k_scatter_x<<<1024, 256, 0, stream>>>(src, dst, cursor, colarr,
                                        ticket + NRANGE, E, rsz);

  int GB = (N / 16 + 3) / 4;  // waves of 16 rows, 4 per block
  int AB = (N + 3) / 4;
  // conv1
  k_gemm_mfma<<<GB, 256, 0, stream>>>(x, fH_W1, fL_W1, dinv, g16, N);
  k_agg_h<<<AB, 256, 0, stream>>>((const __half2*)g16, dinv, rowptr, colarr, b1, h1, N);
  // conv2
  k_gemm_mfma<<<GB, 256, 0, stream>>>(h1, fH_W2, fL_W2, dinv, g16, N);
  k_agg_h<<<AB, 256, 0, stream>>>((const __half2*)g16, dinv, rowptr, colarr, b2, h2, N);
  // head: A = h2 @ Wh1_top, B = h2 @ Wh1_bot
  k_gemm_mfma<<<GB, 256, 0, stream>>>(h2, fH_Wa, fL_Wa, nullptr, A16, N);
  k_gemm_mfma<<<GB, 256, 0, stream>>>(h2, fH_Wb, fL_Wb, nullptr, B16, N);
  k_pairs_h<<<(P + 3) / 4, 256, 0, stream>>>((const __half2*)A16, (const __half2*)B16,
                                             pairs, bh1, Wh2, bh2, (float*)d_out, P);
}

// Round 6
// 413.571 us; speedup vs baseline: 1.6561x; 1.6561x over previous
//
#include <hip/hip_runtime.h>
#include <hip/hip_fp16.h>

// ---------------------------------------------------------------------------
// LinkPredictionGNN: 2x GCNConv (self-loops, sym-norm) + pair MLP head.
//   CSR build: bucket hist -> scan -> multisplit -> per-bucket LDS sort
//   g1 = fp16( dinv * (x @ W1) )                        [k_gemm_mfma]
//   h1 = relu(dinv * (gather-sum g1 + g1) + b1)         [agg_h, fp16 gather]
//   g2 = fp16( dinv * (h1 @ W2) )                       [k_gemm_mfma]
//   h2 = relu(dinv * (gather-sum g2 + g2) + b2)         [agg_h]
//   A = fp16(h2 @ Wh1_top), B = fp16(h2 @ Wh1_bot)      [k_gemm_mfma x2]
//   out[p] = relu(A[p0]+B[p1]+bh1) . Wh2 + bh2          [pairs_h]
//
// R1/R4 lesson: random 4B global writes/atomics carry ~10x line-writeback
// amplification no matter how blocks are placed (XCC pinning regressed).
// R5: CSR build rewritten as 2-level bucket sort:
//   - multisplit writes ~170B contiguous segments per bucket per 4096-edge
//     batch (amp ~1.2x), edges packed (d_local<<16|src)  [needs N<65536]
//   - final per-node placement in one block per bucket with LDS-only
//     histogram/scan/cursors -> zero global random atomics.
// R2: fp16 message/A/B tables (absmax 4.9e-4 < 1.5e-3 threshold).
// R3: double-bf16-split MFMA GEMM (Ah.Bh+Al.Bh+Ah.Bl), no LDS/barriers.
// ---------------------------------------------------------------------------

#define BSH 9                 // log2 nodes per bucket
#define BSZ (1 << BSH)        // 512 nodes per bucket
#define MSB 4096              // edges per multisplit batch/block

typedef __attribute__((ext_vector_type(8))) short bf16x8;
typedef __attribute__((ext_vector_type(4))) float f32x4;

__global__ __launch_bounds__(256) void k_zero_i32(int* __restrict__ p, int n) {
  int i = blockIdx.x * 256 + threadIdx.x;
  if (i < n) p[i] = 0;
}

// per-block LDS histogram of dst into buckets of BSZ nodes
__global__ __launch_bounds__(256) void k_bucket_hist(const int* __restrict__ dst,
                                                     int* __restrict__ gcnt,
                                                     int e, int kb) {
  __shared__ int h[128];
  int tid = threadIdx.x;
  if (tid < kb) h[tid] = 0;
  __syncthreads();
  int stride = gridDim.x * 256;
  for (int i = blockIdx.x * 256 + tid; i < e; i += stride) {
    int d = __builtin_nontemporal_load(&dst[i]);
    atomicAdd(&h[d >> BSH], 1);
  }
  __syncthreads();
  if (tid < kb) atomicAdd(&gcnt[tid], h[tid]);
}

// 1 block, 128 threads: exclusive scan of bucket counts -> gbase, gcur
__global__ __launch_bounds__(128) void k_bucket_scan(const int* __restrict__ gcnt,
                                                     int* __restrict__ gbase,
                                                     int* __restrict__ gcur,
                                                     int kb) {
  __shared__ int ws[2];
  int t = threadIdx.x;
  int lane = t & 63, w = t >> 6;
  int v = (t < kb) ? gcnt[t] : 0;
  int orig = v;
#pragma unroll
  for (int o = 1; o < 64; o <<= 1) {
    int u = __shfl_up(v, o, 64);
    if (lane >= o) v += u;
  }
  if (lane == 63) ws[w] = v;
  __syncthreads();
  int ex = ((w == 1) ? ws[0] : 0) + v - orig;
  if (t < kb) { gbase[t] = ex; gcur[t] = ex; }
  if (t == kb - 1) gbase[kb] = ex + orig;
}

// multisplit: one 4096-edge batch per block; per-edge intra-bucket rank from
// LDS histogram; one global atomic per bucket per batch reserves a contiguous
// segment; packed edge = (d_local << 16) | src   [valid: src < 65536]
__global__ __launch_bounds__(256) void k_multisplit(const int* __restrict__ src,
                                                    const int* __restrict__ dst,
                                                    int* __restrict__ gcur,
                                                    int* __restrict__ tmp,
                                                    int e, int kb) {
  __shared__ int h[128], base[128];
  int tid = threadIdx.x;
  if (tid < kb) h[tid] = 0;
  __syncthreads();
  int i0 = blockIdx.x * MSB + tid;
  int d[16], rk[16];
#pragma unroll
  for (int u = 0; u < 16; ++u) {
    int i = i0 + u * 256;
    if (i < e) {
      d[u] = __builtin_nontemporal_load(&dst[i]);
      rk[u] = atomicAdd(&h[d[u] >> BSH], 1);
    }
  }
  __syncthreads();
  if (tid < kb && h[tid] > 0) base[tid] = atomicAdd(&gcur[tid], h[tid]);
  __syncthreads();
#pragma unroll
  for (int u = 0; u < 16; ++u) {
    int i = i0 + u * 256;
    if (i < e) {
      int s = __builtin_nontemporal_load(&src[i]);
      tmp[base[d[u] >> BSH] + rk[u]] = ((d[u] & (BSZ - 1)) << 16) | s;
    }
  }
}

// one block per bucket: per-node degree + scan + cursor scatter, all in LDS.
// Writes rowptr, dinv, colarr for this bucket's contiguous region.
__global__ __launch_bounds__(512) void k_bucket_build(
    const int* __restrict__ tmp, const int* __restrict__ gbase,
    int* __restrict__ rowptr, float* __restrict__ dinv,
    int* __restrict__ colarr, int n, int kb, int e) {
  __shared__ int dl[BSZ], cl[BSZ], ws[8];
  int t = threadIdx.x, b = blockIdx.x;
  int s0 = gbase[b], s1 = gbase[b + 1];
  dl[t] = 0;
  __syncthreads();
  for (int j = s0 + t; j < s1; j += 512)
    atomicAdd(&dl[((unsigned)tmp[j]) >> 16], 1);
  __syncthreads();
  int lane = t & 63, w = t >> 6;
  int v = dl[t], orig = v;
#pragma unroll
  for (int o = 1; o < 64; o <<= 1) {
    int u = __shfl_up(v, o, 64);
    if (lane >= o) v += u;
  }
  if (lane == 63) ws[w] = v;
  __syncthreads();
  if (t == 0) {
    int a = 0;
#pragma unroll
    for (int k = 0; k < 8; ++k) { int x = ws[k]; ws[k] = a; a += x; }
  }
  __syncthreads();
  int ex = ws[w] + v - orig;
  cl[t] = ex;
  int node = (b << BSH) + t;
  if (node < n) {
    rowptr[node] = s0 + ex;
    dinv[node] = rsqrtf((float)(orig + 1));  // +1 self loop
  }
  if (b == kb - 1 && t == 0) rowptr[n] = e;
  __syncthreads();
  for (int j = s0 + t; j < s1; j += 512) {
    int p = tmp[j];
    int r = atomicAdd(&cl[((unsigned)p) >> 16], 1);
    colarr[s0 + r] = p & 0xFFFF;
  }
}

// --- MFMA GEMM machinery ----------------------------------------------------
// Exact split: x = hi(bf16, trunc) + lo(bf16, trunc) + O(2^-17 |x|).
__device__ __forceinline__ void split8(const float* v, bf16x8& hi, bf16x8& lo) {
#pragma unroll
  for (int j = 0; j < 8; ++j) {
    unsigned u = __float_as_uint(v[j]);
    hi[j] = (short)(u >> 16);
    float lf = v[j] - __uint_as_float(u & 0xffff0000u);
    lo[j] = (short)(__float_as_uint(lf) >> 16);
  }
}

// Precompute B-operand bf16 hi/lo fragments for the 4 weight matrices.
// Slot g = ((w*8 + t)*4 + s)*64 + lane ; lane holds B[k=s*32+quad*8+j][n=16t+(lane&15)]
__global__ __launch_bounds__(256) void k_prep_w(
    const float* __restrict__ W1, const float* __restrict__ W2,
    const float* __restrict__ Wh1, short* __restrict__ fragH,
    short* __restrict__ fragL) {
  int g = blockIdx.x * 256 + threadIdx.x;
  if (g >= 4 * 2048) return;
  int w = g >> 11;
  int rem = g & 2047;
  int lane = rem & 63;
  int ts = rem >> 6;          // t*4 + s
  int t = ts >> 2, s = ts & 3;
  int n = (t << 4) + (lane & 15);
  int k0 = s * 32 + (lane >> 4) * 8;
  const float* W = (w == 0) ? W1 : (w == 1) ? W2 : (w == 2) ? Wh1 : (Wh1 + 128 * 128);
  short h[8], l[8];
#pragma unroll
  for (int j = 0; j < 8; ++j) {
    float x = W[(k0 + j) * 128 + n];
    unsigned u = __float_as_uint(x);
    h[j] = (short)(u >> 16);
    float lf = x - __uint_as_float(u & 0xffff0000u);
    l[j] = (short)(__float_as_uint(lf) >> 16);
  }
  ((int4*)fragH)[g] = *(int4*)h;
  ((int4*)fragL)[g] = *(int4*)l;
}

// C16[n,128] = fp16( rowscale * (X[n,128] @ W) ) via 16x16x32 bf16 MFMA.
// One wave = 16 rows x 128 cols. No LDS, no barriers.
__global__ __launch_bounds__(256) void k_gemm_mfma(
    const float* __restrict__ X, const short* __restrict__ fragH,
    const short* __restrict__ fragL, const float* __restrict__ rowscale,
    __half* __restrict__ C16, int n) {
  int wid = threadIdx.x >> 6, lane = threadIdx.x & 63;
  int r0 = (blockIdx.x * 4 + wid) * 16;
  if (r0 >= n) return;
  int m = lane & 15, quad = lane >> 4;
  const float* xrow = X + (size_t)(r0 + m) * 128;
  f32x4 acc[8];
#pragma unroll
  for (int t = 0; t < 8; ++t) acc[t] = (f32x4)(0.f);
  const int4* FH = (const int4*)fragH;
  const int4* FL = (const int4*)fragL;
#pragma unroll
  for (int s = 0; s < 4; ++s) {
    int k0 = s * 32 + quad * 8;
    float xv[8];
    *(float4*)&xv[0] = *(const float4*)(xrow + k0);
    *(float4*)&xv[4] = *(const float4*)(xrow + k0 + 4);
    bf16x8 ah, al;
    split8(xv, ah, al);
#pragma unroll
    for (int t = 0; t < 8; ++t) {
      int idx = (t * 4 + s) * 64 + lane;
      bf16x8 bh = *(const bf16x8*)&FH[idx];
      bf16x8 bl = *(const bf16x8*)&FL[idx];
      acc[t] = __builtin_amdgcn_mfma_f32_16x16x32_bf16(ah, bh, acc[t], 0, 0, 0);
      acc[t] = __builtin_amdgcn_mfma_f32_16x16x32_bf16(al, bh, acc[t], 0, 0, 0);
      acc[t] = __builtin_amdgcn_mfma_f32_16x16x32_bf16(ah, bl, acc[t], 0, 0, 0);
    }
  }
  // C/D layout: col = lane&15, row = quad*4 + reg   [m89-verified mapping]
  float sc[4];
#pragma unroll
  for (int r = 0; r < 4; ++r)
    sc[r] = rowscale ? rowscale[r0 + quad * 4 + r] : 1.f;
#pragma unroll
  for (int t = 0; t < 8; ++t) {
#pragma unroll
    for (int r = 0; r < 4; ++r) {
      int row = r0 + quad * 4 + r;
      C16[(size_t)row * 128 + t * 16 + m] = __float2half(acc[t][r] * sc[r]);
    }
  }
}

// out[i,:] = relu(dinv[i] * (g[i,:] + sum_{e in row i} g[col[e],:]) + bias)
// fp16 message table; 64 lanes per row, one half2 (2 cols) per lane.
__global__ __launch_bounds__(256) void k_agg_h(
    const __half2* __restrict__ g2, const float* __restrict__ dinv,
    const int* __restrict__ rowptr, const int* __restrict__ col,
    const float* __restrict__ bias, float* __restrict__ out, int n) {
  int i = blockIdx.x * 4 + (threadIdx.x >> 6);
  int c = threadIdx.x & 63;  // half2 column index
  if (i >= n) return;
  float2 a0 = __half22float2(g2[(size_t)i * 64 + c]);  // self loop
  float2 a1 = make_float2(0.f, 0.f);
  float2 a2 = make_float2(0.f, 0.f);
  float2 a3 = make_float2(0.f, 0.f);
  int beg = rowptr[i], end = rowptr[i + 1];
  int j = beg;
  for (; j + 4 <= end; j += 4) {
    int s0 = __builtin_nontemporal_load(&col[j]);
    int s1 = __builtin_nontemporal_load(&col[j + 1]);
    int s2 = __builtin_nontemporal_load(&col[j + 2]);
    int s3 = __builtin_nontemporal_load(&col[j + 3]);
    float2 v0 = __half22float2(g2[(size_t)s0 * 64 + c]);
    float2 v1 = __half22float2(g2[(size_t)s1 * 64 + c]);
    float2 v2 = __half22float2(g2[(size_t)s2 * 64 + c]);
    float2 v3 = __half22float2(g2[(size_t)s3 * 64 + c]);
    a0.x += v0.x; a0.y += v0.y;
    a1.x += v1.x; a1.y += v1.y;
    a2.x += v2.x; a2.y += v2.y;
    a3.x += v3.x; a3.y += v3.y;
  }
  for (; j < end; ++j) {
    float2 v = __half22float2(g2[(size_t)__builtin_nontemporal_load(&col[j]) * 64 + c]);
    a0.x += v.x; a0.y += v.y;
  }
  float di = dinv[i];
  float2 bi = ((const float2*)bias)[c];
  float2 o;
  o.x = fmaxf(fmaf(di, (a0.x + a1.x) + (a2.x + a3.x), bi.x), 0.f);
  o.y = fmaxf(fmaf(di, (a0.y + a1.y) + (a2.y + a3.y), bi.y), 0.f);
  ((float2*)out)[(size_t)i * 64 + c] = o;
}

// one wave per pair, fp16 A/B tables, half2 per lane
__global__ __launch_bounds__(256) void k_pairs_h(
    const __half2* __restrict__ A, const __half2* __restrict__ B,
    const int* __restrict__ pairs, const float* __restrict__ bh1,
    const float* __restrict__ wh2, const float* __restrict__ bh2,
    float* __restrict__ out, int P) {
  int p = blockIdx.x * 4 + (threadIdx.x >> 6);
  int c = threadIdx.x & 63;
  if (p >= P) return;
  int p0 = pairs[2 * p], p1 = pairs[2 * p + 1];
  float2 av = __half22float2(A[(size_t)p0 * 64 + c]);
  float2 bv = __half22float2(B[(size_t)p1 * 64 + c]);
  float2 bi = ((const float2*)bh1)[c];
  float2 wv = ((const float2*)wh2)[c];
  float v0 = fmaxf(av.x + bv.x + bi.x, 0.f) * wv.x;
  float v1 = fmaxf(av.y + bv.y + bi.y, 0.f) * wv.y;
  float s = v0 + v1;
#pragma unroll
  for (int o = 32; o > 0; o >>= 1) s += __shfl_down(s, o, 64);
  if (c == 0) out[p] = s + bh2[0];
}

extern "C" void kernel_launch(void* const* d_in, const int* in_sizes, int n_in,
                              void* d_out, int out_size, void* d_ws, size_t ws_size,
                              hipStream_t stream) {
  const float* x   = (const float*)d_in[0];
  const int* ei    = (const int*)d_in[1];
  const int* pairs = (const int*)d_in[2];
  const float* W1  = (const float*)d_in[3];
  const float* b1  = (const float*)d_in[4];
  const float* W2  = (const float*)d_in[5];
  const float* b2  = (const float*)d_in[6];
  const float* Wh1 = (const float*)d_in[7];
  const float* bh1 = (const float*)d_in[8];
  const float* Wh2 = (const float*)d_in[9];
  const float* bh2 = (const float*)d_in[10];
  (void)n_in; (void)out_size; (void)ws_size;

  int N = in_sizes[0] / 128;
  int E = in_sizes[1] / 2;
  int P = in_sizes[2] / 2;
  const int* src = ei;
  const int* dst = ei + E;
  int KB = (N + BSZ - 1) >> BSH;  // buckets (98 for N=50000)

  char* wsp = (char*)d_ws;
  size_t off = 0;
  auto alloc = [&](size_t bytes) -> void* {
    void* p = wsp + off;
    off += (bytes + 255) & ~(size_t)255;
    return p;
  };
  __half* g16 = (__half*)alloc((size_t)N * 128 * 2);  // messages; reused as A16
  float* h1   = (float*)alloc((size_t)N * 128 * 4);   // reused as B16 (fp16)
  float* h2   = (float*)alloc((size_t)N * 128 * 4);
  float* dinv = (float*)alloc((size_t)N * 4);
  int* rowptr = (int*)alloc((size_t)(N + 1) * 4);
  int* colarr = (int*)alloc((size_t)E * 4);
  int* tmp    = (int*)alloc((size_t)E * 4);           // packed bucketed edges
  short* fragH = (short*)alloc(4 * 2048 * 8 * 2);     // 128KB
  short* fragL = (short*)alloc(4 * 2048 * 8 * 2);     // 128KB
  int* gcnt  = (int*)alloc((size_t)(KB + 1) * 4);
  int* gbase = (int*)alloc((size_t)(KB + 1) * 4);
  int* gcur  = (int*)alloc((size_t)(KB + 1) * 4);
  __half* A16 = g16;            // g16 dead by the time head runs
  __half* B16 = (__half*)h1;    // h1 dead after conv2 gemm
  // per-W frag bases (2048 slots * 8 shorts each)
  short* fH_W1 = fragH + 0 * 16384;  short* fL_W1 = fragL + 0 * 16384;
  short* fH_W2 = fragH + 1 * 16384;  short* fL_W2 = fragL + 1 * 16384;
  short* fH_Wa = fragH + 2 * 16384;  short* fL_Wa = fragL + 2 * 16384;
  short* fH_Wb = fragH + 3 * 16384;  short* fL_Wb = fragL + 3 * 16384;

  // weight fragment prep (independent of CSR)
  k_prep_w<<<32, 256, 0, stream>>>(W1, W2, Wh1, fragH, fragL);

  // CSR build: hist -> scan -> multisplit -> per-bucket LDS sort
  k_zero_i32<<<1, 256, 0, stream>>>(gcnt, KB + 1);
  k_bucket_hist<<<256, 256, 0, stream>>>(dst, gcnt, E, KB);
  k_bucket_scan<<<1, 128, 0, stream>>>(gcnt, gbase, gcur, KB);
  k_multisplit<<<(E + MSB - 1) / MSB, 256, 0, stream>>>(src, dst, gcur, tmp, E, KB);
  k_bucket_build<<<KB, 512, 0, stream>>>(tmp, gbase, rowptr, dinv, colarr, N, KB, E);

  int GB = (N / 16 + 3) / 4;  // waves of 16 rows, 4 per block
  int AB = (N + 3) / 4;
  // conv1
  k_gemm_mfma<<<GB, 256, 0, stream>>>(x, fH_W1, fL_W1, dinv, g16, N);
  k_agg_h<<<AB, 256, 0, stream>>>((const __half2*)g16, dinv, rowptr, colarr, b1, h1, N);
  // conv2
  k_gemm_mfma<<<GB, 256, 0, stream>>>(h1, fH_W2, fL_W2, dinv, g16, N);
  k_agg_h<<<AB, 256, 0, stream>>>((const __half2*)g16, dinv, rowptr, colarr, b2, h2, N);
  // head: A = h2 @ Wh1_top, B = h2 @ Wh1_bot
  k_gemm_mfma<<<GB, 256, 0, stream>>>(h2, fH_Wa, fL_Wa, nullptr, A16, N);
  k_gemm_mfma<<<GB, 256, 0, stream>>>(h2, fH_Wb, fL_Wb, nullptr, B16, N);
  k_pairs_h<<<(P + 3) / 4, 256, 0, stream>>>((const __half2*)A16, (const __half2*)B16,
                                             pairs, bh1, Wh2, bh2, (float*)d_out, P);
}